// Round 2
// baseline (847.374 us; speedup 1.0000x reference)
//
#include <hip/hip_runtime.h>
#include <stdint.h>
#include <stddef.h>

// ---------------- common helpers ----------------

typedef __bf16 bf16x8 __attribute__((ext_vector_type(8)));
typedef float  f32x4  __attribute__((ext_vector_type(4)));

#define MFMA16x16(a,b,c) __builtin_amdgcn_mfma_f32_16x16x32_bf16((a),(b),(c),0,0,0)

__device__ __forceinline__ uint16_t f2bf(float f){
  union { float f; uint32_t u; } v; v.f = f;
  uint32_t u = v.u + 0x7fffu + ((v.u >> 16) & 1u);
  return (uint16_t)(u >> 16);
}
__device__ __forceinline__ float bf2f(uint16_t h){
  union { uint32_t u; float f; } v; v.u = ((uint32_t)h) << 16;
  return v.f;
}
__device__ __forceinline__ bf16x8 load_frag(const uint16_t* p){
  uint4 u = *reinterpret_cast<const uint4*>(p);
  return __builtin_bit_cast(bf16x8, u);
}
__device__ __forceinline__ f32x4 fzero(){
  f32x4 z = {0.f, 0.f, 0.f, 0.f};
  return z;
}
__device__ __forceinline__ uint32_t pack2(float a, float b){
  return (uint32_t)f2bf(a) | ((uint32_t)f2bf(b) << 16);
}

// ---------------- 1) transpose + f32->bf16 convert ----------------
// in: R x C (f32, row-major)  ->  out: C x R (bf16, row-major)
__global__ __launch_bounds__(256) void k_transpose_cvt(const float* __restrict__ in,
                                                       uint16_t* __restrict__ out,
                                                       int R, int C){
  __shared__ float t[32][33];
  const int tc = blockIdx.x * 32;   // C-dim tile
  const int tr = blockIdx.y * 32;   // R-dim tile
  const int j = threadIdx.x & 31, i0 = threadIdx.x >> 5;
  for(int ii = 0; ii < 4; ++ii){
    int r = i0 + ii * 8;
    t[r][j] = in[(size_t)(tr + r) * C + tc + j];
  }
  __syncthreads();
  for(int ii = 0; ii < 4; ++ii){
    int c = i0 + ii * 8;
    out[(size_t)(tc + c) * R + tr + j] = f2bf(t[j][c]);
  }
}

// ---------------- 2) down-proj + RMSNorm via MFMA ----------------
// x: [4096][1024] f32 (converted to bf16 during LDS staging)
// wdt: [192][1024] bf16 (w_down^T), rms_w: [192] f32
// h_out: [4096][192] bf16
// grid 128, block 256 (4 waves): tile 32m x 192n, wave = 32m x 48n, K-loop 64.
__global__ __launch_bounds__(256) void k_down_mfma(const float* __restrict__ x,
                                                   const uint16_t* __restrict__ wdt,
                                                   const float* __restrict__ rms_w,
                                                   uint16_t* __restrict__ h_out){
  __shared__ __align__(16) uint16_t as[32 * 64];
  __shared__ float hsq[32];
  const int tid  = threadIdx.x;
  const int wave = tid >> 6, lane = tid & 63;
  const int ml = lane & 15, qd = lane >> 4;
  const int m0 = blockIdx.x * 32;
  const int n0w = wave * 48;
  if(tid < 32) hsq[tid] = 0.f;

  f32x4 acc[2][3];
#pragma unroll
  for(int mt = 0; mt < 2; ++mt)
#pragma unroll
    for(int nt = 0; nt < 3; ++nt) acc[mt][nt] = fzero();

  const int srow = tid >> 3, sc = tid & 7;    // staging: 32 rows x 8 chunks
  for(int kt = 0; kt < 16; ++kt){
    // stage x (f32 -> bf16) into LDS, XOR-swizzled 16B chunks
    const float* src = x + (size_t)(m0 + srow) * 1024 + kt * 64 + sc * 8;
    float4 a = *reinterpret_cast<const float4*>(src);
    float4 b = *reinterpret_cast<const float4*>(src + 4);
    uint4 pk;
    pk.x = pack2(a.x, a.y); pk.y = pack2(a.z, a.w);
    pk.z = pack2(b.x, b.y); pk.w = pack2(b.z, b.w);
    __syncthreads();
    *reinterpret_cast<uint4*>(as + srow * 64 + ((sc ^ (srow & 7)) * 8)) = pk;
    __syncthreads();
#pragma unroll
    for(int kk = 0; kk < 2; ++kk){
      bf16x8 af[2];
#pragma unroll
      for(int mt = 0; mt < 2; ++mt){
        int row = mt * 16 + ml;
        af[mt] = load_frag(as + row * 64 + (((kk * 4 + qd) ^ (row & 7)) * 8));
      }
#pragma unroll
      for(int nt = 0; nt < 3; ++nt){
        bf16x8 bfr = load_frag(wdt + (size_t)(n0w + nt * 16 + ml) * 1024 + kt * 64 + kk * 32 + qd * 8);
#pragma unroll
        for(int mt = 0; mt < 2; ++mt)
          acc[mt][nt] = MFMA16x16(af[mt], bfr, acc[mt][nt]);
      }
    }
  }
  __syncthreads();
  // sum of squares per row (over this wave's 48 cols), reduce across ml, LDS-atomic across waves
#pragma unroll
  for(int mt = 0; mt < 2; ++mt)
#pragma unroll
    for(int r = 0; r < 4; ++r){
      float s = acc[mt][0][r]*acc[mt][0][r] + acc[mt][1][r]*acc[mt][1][r] + acc[mt][2][r]*acc[mt][2][r];
#pragma unroll
      for(int off = 1; off < 16; off <<= 1) s += __shfl_xor(s, off);
      if(ml == 0) atomicAdd(&hsq[mt * 16 + qd * 4 + r], s);
    }
  __syncthreads();
  float rw[3];
#pragma unroll
  for(int nt = 0; nt < 3; ++nt) rw[nt] = rms_w[n0w + nt * 16 + ml];
#pragma unroll
  for(int mt = 0; mt < 2; ++mt)
#pragma unroll
    for(int r = 0; r < 4; ++r){
      int row = mt * 16 + qd * 4 + r;
      float scl = rsqrtf(hsq[row] * (1.0f / 192.0f) + 1e-6f);
#pragma unroll
      for(int nt = 0; nt < 3; ++nt)
        h_out[(size_t)(m0 + row) * 192 + n0w + nt * 16 + ml] = f2bf(acc[mt][nt][r] * scl * rw[nt]);
    }
}

// ---------------- 3) up-proj GEMM + fused head-split/RoPE/transpose ----------------
// hmat: [4096][192] bf16, wt: [9216][192] bf16 (w_up^T)
// writes q_t,k_t: [b,h,s,d] (RoPE on d in [128,160)), v_t: [b,h,d,s]
// grid (36, 128), block 256: tile 32m x 256n, wave 32m x 64n (= 4 d-values x 16 h).
__global__ __launch_bounds__(256) void k_gemm_up(const uint16_t* __restrict__ hmat,
                                                 const uint16_t* __restrict__ wt,
                                                 uint16_t* __restrict__ q_t,
                                                 uint16_t* __restrict__ k_t,
                                                 uint16_t* __restrict__ v_t){
  const int wave = threadIdx.x >> 6, lane = threadIdx.x & 63;
  const int ml = lane & 15, qd = lane >> 4;
  const int m0 = blockIdx.y * 32;
  const int n0 = blockIdx.x * 256 + wave * 64;
  const int which = n0 / 3072;
  const int d0 = (n0 % 3072) >> 4;            // 4 consecutive d per wave, h = ml
  bf16x8 af[2][6];
#pragma unroll
  for(int mt = 0; mt < 2; ++mt)
#pragma unroll
    for(int kk = 0; kk < 6; ++kk)
      af[mt][kk] = load_frag(hmat + (size_t)(m0 + mt * 16 + ml) * 192 + kk * 32 + qd * 8);
  f32x4 acc[4][2];
#pragma unroll
  for(int nt = 0; nt < 4; ++nt){ acc[nt][0] = fzero(); acc[nt][1] = fzero(); }
#pragma unroll
  for(int nt = 0; nt < 4; ++nt){
#pragma unroll
    for(int kk = 0; kk < 6; ++kk){
      bf16x8 b = load_frag(wt + (size_t)(n0 + nt * 16 + ml) * 192 + kk * 32 + qd * 8);
      acc[nt][0] = MFMA16x16(af[0][kk], b, acc[nt][0]);
      acc[nt][1] = MFMA16x16(af[1][kk], b, acc[nt][1]);
    }
  }
  // epilogue: RoPE (register-local pairs) + scatter to q_t/k_t/v_t
  if(which < 2){
    uint16_t* dst = which ? k_t : q_t;
#pragma unroll
    for(int mt = 0; mt < 2; ++mt)
#pragma unroll
      for(int r = 0; r < 4; ++r){
        int tok = m0 + mt * 16 + qd * 4 + r;
        int b = tok >> 11, s = tok & 2047;
        float v0 = acc[0][mt][r], v1 = acc[1][mt][r];
        float v2 = acc[2][mt][r], v3 = acc[3][mt][r];
        if(d0 >= 128 && d0 < 160){
#pragma unroll
          for(int p = 0; p < 2; ++p){
            int fi = (d0 + 2 * p - 128) >> 1;
            float invf = __expf(-(float)fi * 0.5756462732485114f); // ln(10000)/16
            float sn, cs;
            sincosf((float)s * invf, &sn, &cs);
            float e = p ? v2 : v0, o = p ? v3 : v1;
            float ne = e * cs - o * sn, no = o * cs + e * sn;
            if(p){ v2 = ne; v3 = no; } else { v0 = ne; v1 = no; }
          }
        }
        uint2 pk; pk.x = pack2(v0, v1); pk.y = pack2(v2, v3);
        *reinterpret_cast<uint2*>(dst + (((size_t)b * 16 + ml) * 2048 + s) * 192 + d0) = pk;
      }
  } else {
#pragma unroll
    for(int mt = 0; mt < 2; ++mt){
      int tok0 = m0 + mt * 16 + qd * 4;
      int b = tok0 >> 11, s0 = tok0 & 2047;
#pragma unroll
      for(int nt = 0; nt < 4; ++nt){
        uint2 pk;
        pk.x = pack2(acc[nt][mt][0], acc[nt][mt][1]);
        pk.y = pack2(acc[nt][mt][2], acc[nt][mt][3]);
        *reinterpret_cast<uint2*>(v_t + (((size_t)b * 16 + ml) * 192 + d0 + nt) * 2048 + s0) = pk;
      }
    }
  }
}

// ---------------- 4) causal flash attention ----------------
// q_t,k_t: [bh][s][192] bf16; v_t: [bh][192][s] bf16; attn_out: [b*2048+s][h*192+d] bf16
// grid (32 q-tiles, 32 bh), block 256 (4 waves x 16 q-rows). K-tile 64.
// Single 24KB LDS buffer shared for Q-stage, K-tile, then V-tile (4 barriers/iter).
// XOR swizzle on 16B chunks: chunk' = chunk ^ (row & 7).
__global__ __launch_bounds__(256, 4) void k_attn(const uint16_t* __restrict__ q_t,
                                                 const uint16_t* __restrict__ k_t,
                                                 const uint16_t* __restrict__ v_t,
                                                 uint16_t* __restrict__ attn_out){
  __shared__ __align__(16) uint16_t kv[64 * 192];   // K [64][192] or V^T [192][64]
  __shared__ __align__(16) uint16_t ps[4][16 * 64];
  const int tid  = threadIdx.x;
  const int wave = tid >> 6;
  const int lane = tid & 63;
  const int ml   = lane & 15;
  const int qd   = lane >> 4;
  const int qt   = (int)gridDim.x - 1 - (int)blockIdx.x;   // heavy blocks first
  const int bh   = blockIdx.y;
  const int q0   = qt * 64;
  const size_t kbase = (size_t)bh * 2048 * 192;
  const size_t vbase = (size_t)bh * 192 * 2048;

  // stage Q into kv, pull A-frags to registers
  {
    const uint16_t* qsrc = q_t + kbase + (size_t)q0 * 192;
    for(int it = 0; it < 6; ++it){
      int idx = it * 256 + tid;               // 64 rows x 24 chunks
      int row = idx / 24, c = idx % 24;
      uint4 u = *reinterpret_cast<const uint4*>(qsrc + (size_t)row * 192 + c * 8);
      *reinterpret_cast<uint4*>(kv + row * 192 + ((c ^ (row & 7)) * 8)) = u;
    }
  }
  __syncthreads();
  bf16x8 qf[6];
  {
    int row = wave * 16 + ml;
#pragma unroll
    for(int kk = 0; kk < 6; ++kk){
      int c = (kk * 4 + qd) ^ (row & 7);
      qf[kk] = load_frag(kv + row * 192 + c * 8);
    }
  }

  f32x4 o[12];
#pragma unroll
  for(int i = 0; i < 12; ++i) o[i] = fzero();
  float mrow[4] = {-3e38f, -3e38f, -3e38f, -3e38f};
  float lrow[4] = {0.f, 0.f, 0.f, 0.f};
  const float scale = 0.07216878364870322f;   // 1/sqrt(192)

  const int ktiles = qt + 1;
  for(int kt = 0; kt < ktiles; ++kt){
    __syncthreads();                           // prior reads of kv done
    for(int it = 0; it < 6; ++it){             // stage K tile [64][192]
      int idx = it * 256 + tid;
      int row = idx / 24, c = idx % 24;
      uint4 u = *reinterpret_cast<const uint4*>(k_t + kbase + (size_t)(kt * 64 + row) * 192 + c * 8);
      *reinterpret_cast<uint4*>(kv + row * 192 + ((c ^ (row & 7)) * 8)) = u;
    }
    __syncthreads();

    // S = Q K^T (per wave: 16 q-rows x 64 keys)
    float pv[4][4];
#pragma unroll
    for(int nt = 0; nt < 4; ++nt){
      f32x4 a = fzero();
      int row = nt * 16 + ml;
#pragma unroll
      for(int kk = 0; kk < 6; ++kk){
        int c = (kk * 4 + qd) ^ (row & 7);
        bf16x8 b = load_frag(kv + row * 192 + c * 8);
        a = MFMA16x16(qf[kk], b, a);
      }
#pragma unroll
      for(int r = 0; r < 4; ++r) pv[nt][r] = a[r];
    }

    const bool diag = (kt == qt);
#pragma unroll
    for(int nt = 0; nt < 4; ++nt)
#pragma unroll
      for(int r = 0; r < 4; ++r){
        float v = pv[nt][r] * scale;
        if(diag){
          int i = q0 + wave * 16 + qd * 4 + r;
          int j = kt * 64 + nt * 16 + ml;
          if(j > i) v = -1e9f;
        }
        pv[nt][r] = v;
      }

    float alpha[4];
#pragma unroll
    for(int r = 0; r < 4; ++r){
      float mx = fmaxf(fmaxf(pv[0][r], pv[1][r]), fmaxf(pv[2][r], pv[3][r]));
#pragma unroll
      for(int off = 1; off < 16; off <<= 1)
        mx = fmaxf(mx, __shfl_xor(mx, off));
      float mn = fmaxf(mrow[r], mx);
      alpha[r] = __expf(mrow[r] - mn);
      mrow[r] = mn;
    }
#pragma unroll
    for(int r = 0; r < 4; ++r){
      float rs = 0.f;
#pragma unroll
      for(int nt = 0; nt < 4; ++nt){
        float e = __expf(pv[nt][r] - mrow[r]);
        pv[nt][r] = e;
        rs += e;
      }
#pragma unroll
      for(int off = 1; off < 16; off <<= 1)
        rs += __shfl_xor(rs, off);
      lrow[r] = lrow[r] * alpha[r] + rs;
    }
#pragma unroll
    for(int dt = 0; dt < 12; ++dt){
      o[dt][0] *= alpha[0]; o[dt][1] *= alpha[1];
      o[dt][2] *= alpha[2]; o[dt][3] *= alpha[3];
    }
    __syncthreads();                           // all waves' K reads done
    for(int it = 0; it < 6; ++it){             // stage V^T tile [192][64] into kv
      int idx = it * 256 + tid;
      int d = idx >> 3, c = idx & 7;
      uint4 u = *reinterpret_cast<const uint4*>(v_t + vbase + (size_t)d * 2048 + kt * 64 + c * 8);
      *reinterpret_cast<uint4*>(kv + d * 64 + ((c ^ (d & 7)) * 8)) = u;
    }
    // P (C-layout) -> LDS bf16 (A-layout readback); ps is wave-private
#pragma unroll
    for(int nt = 0; nt < 4; ++nt)
#pragma unroll
      for(int r = 0; r < 4; ++r){
        int rp = qd * 4 + r;
        int col = nt * 16 + ml;
        int c = (col >> 3) ^ (rp & 7);
        ps[wave][rp * 64 + c * 8 + (col & 7)] = f2bf(pv[nt][r]);
      }
    __syncthreads();
    // O += P V
#pragma unroll
    for(int kk2 = 0; kk2 < 2; ++kk2){
      int cp = (kk2 * 4 + qd) ^ (ml & 7);
      bf16x8 pa = load_frag(&ps[wave][ml * 64 + cp * 8]);
#pragma unroll
      for(int dt = 0; dt < 12; ++dt){
        int row = dt * 16 + ml;
        int cv = (kk2 * 4 + qd) ^ (row & 7);
        bf16x8 vb = load_frag(kv + row * 64 + cv * 8);
        o[dt] = MFMA16x16(pa, vb, o[dt]);
      }
    }
  }

  const int hh = bh & 15, b = bh >> 4;
#pragma unroll
  for(int r = 0; r < 4; ++r){
    int i = q0 + wave * 16 + qd * 4 + r;
    float inv = 1.0f / lrow[r];
    size_t obase = ((size_t)b * 2048 + i) * 3072 + hh * 192;
#pragma unroll
    for(int dt = 0; dt < 12; ++dt)
      attn_out[obase + dt * 16 + ml] = f2bf(o[dt][r] * inv);
  }
}

// ---------------- 5) out-proj GEMM (register MFMA, K=3072) ----------------
// a: [4096][3072] bf16, wt: [1024][3072] bf16 (w_o^T), out: [4096][1024] f32
// grid (8, 64), block 256: block tile 64m x 128n, wave 32m x 64n.
__global__ __launch_bounds__(256) void k_gemm_o(const uint16_t* __restrict__ a,
                                                const uint16_t* __restrict__ wt,
                                                float* __restrict__ out){
  const int wave = threadIdx.x >> 6, lane = threadIdx.x & 63;
  const int ml = lane & 15, qd = lane >> 4;
  const int m0 = blockIdx.y * 64 + (wave >> 1) * 32;
  const int n0 = blockIdx.x * 128 + (wave & 1) * 64;
  f32x4 acc[2][4];
#pragma unroll
  for(int mt = 0; mt < 2; ++mt)
#pragma unroll
    for(int nt = 0; nt < 4; ++nt) acc[mt][nt] = fzero();
  for(int kk = 0; kk < 96; ++kk){
    bf16x8 af[2], bfr[4];
#pragma unroll
    for(int mt = 0; mt < 2; ++mt)
      af[mt] = load_frag(a + (size_t)(m0 + mt * 16 + ml) * 3072 + kk * 32 + qd * 8);
#pragma unroll
    for(int nt = 0; nt < 4; ++nt)
      bfr[nt] = load_frag(wt + (size_t)(n0 + nt * 16 + ml) * 3072 + kk * 32 + qd * 8);
#pragma unroll
    for(int mt = 0; mt < 2; ++mt)
#pragma unroll
      for(int nt = 0; nt < 4; ++nt)
        acc[mt][nt] = MFMA16x16(af[mt], bfr[nt], acc[mt][nt]);
  }
#pragma unroll
  for(int mt = 0; mt < 2; ++mt)
#pragma unroll
    for(int nt = 0; nt < 4; ++nt)
#pragma unroll
      for(int r = 0; r < 4; ++r){
        int row = m0 + mt * 16 + qd * 4 + r;
        int col = n0 + nt * 16 + ml;
        out[(size_t)row * 1024 + col] = acc[mt][nt][r];
      }
}

// ---------------- launch ----------------

extern "C" void kernel_launch(void* const* d_in, const int* in_sizes, int n_in,
                              void* d_out, int out_size, void* d_ws, size_t ws_size,
                              hipStream_t stream) {
  (void)in_sizes; (void)n_in; (void)out_size; (void)ws_size;
  const float* x      = (const float*)d_in[0];
  // d_in[1] = mask (int32) — causal, handled analytically
  const float* w_down = (const float*)d_in[2];
  const float* rms_w  = (const float*)d_in[3];
  const float* w_up   = (const float*)d_in[4];
  const float* w_o    = (const float*)d_in[5];
  float* out = (float*)d_out;

  char* ws = (char*)d_ws;
  uint16_t* h_bf   = (uint16_t*)(ws);                     // 1,572,864 B
  uint16_t* w_up_t = (uint16_t*)(ws + 1572864);           // 3,538,944 B
  uint16_t* w_o_t  = (uint16_t*)(ws + 5111808);           // 6,291,456 B
  uint16_t* w_dn_t = (uint16_t*)(ws + 11403264);          //   393,216 B
  uint16_t* q_tb   = (uint16_t*)(ws + 11796480);          // 25,165,824 B
  uint16_t* k_tb   = (uint16_t*)(ws + 36962304);          // 25,165,824 B
  uint16_t* v_tb   = (uint16_t*)(ws + 62128128);          // 25,165,824 B
  uint16_t* attnO  = (uint16_t*)(ws + 87293952);          // 25,165,824 B (end 112.5 MB)

  k_transpose_cvt<<<dim3(288, 6), 256, 0, stream>>>(w_up, w_up_t, 192, 9216);
  k_transpose_cvt<<<dim3(32, 96), 256, 0, stream>>>(w_o,  w_o_t,  3072, 1024);
  k_transpose_cvt<<<dim3(6, 32),  256, 0, stream>>>(w_down, w_dn_t, 1024, 192);
  k_down_mfma<<<128, 256, 0, stream>>>(x, w_dn_t, rms_w, h_bf);
  k_gemm_up<<<dim3(36, 128), 256, 0, stream>>>(h_bf, w_up_t, q_tb, k_tb, v_tb);
  k_attn<<<dim3(32, 32), 256, 0, stream>>>(q_tb, k_tb, v_tb, attnO);
  k_gemm_o<<<dim3(8, 64), 256, 0, stream>>>(attnO, w_o_t, out);
}

// Round 3
// 459.760 us; speedup vs baseline: 1.8431x; 1.8431x over previous
//
#include <hip/hip_runtime.h>
#include <stdint.h>
#include <stddef.h>

// ---------------- common helpers ----------------

typedef __bf16 bf16x8 __attribute__((ext_vector_type(8)));
typedef float  f32x4  __attribute__((ext_vector_type(4)));

#define MFMA16x16(a,b,c) __builtin_amdgcn_mfma_f32_16x16x32_bf16((a),(b),(c),0,0,0)

__device__ __forceinline__ uint16_t f2bf(float f){
  union { float f; uint32_t u; } v; v.f = f;
  uint32_t u = v.u + 0x7fffu + ((v.u >> 16) & 1u);
  return (uint16_t)(u >> 16);
}
__device__ __forceinline__ bf16x8 load_frag(const uint16_t* p){
  uint4 u = *reinterpret_cast<const uint4*>(p);
  return __builtin_bit_cast(bf16x8, u);
}
__device__ __forceinline__ f32x4 fzero(){
  f32x4 z = {0.f, 0.f, 0.f, 0.f};
  return z;
}
__device__ __forceinline__ uint32_t pack2(float a, float b){
  return (uint32_t)f2bf(a) | ((uint32_t)f2bf(b) << 16);
}
// async global->LDS DMA, 16B per lane, LDS dst = wave-uniform base + lane*16
__device__ __forceinline__ void gl2lds16(const uint16_t* g, uint16_t* l){
  __builtin_amdgcn_global_load_lds(
      (const __attribute__((address_space(1))) uint32_t*)g,
      (__attribute__((address_space(3))) uint32_t*)l,
      16, 0, 0);
}

// ---------------- 1) transpose + f32->bf16 convert ----------------
__global__ __launch_bounds__(256) void k_transpose_cvt(const float* __restrict__ in,
                                                       uint16_t* __restrict__ out,
                                                       int R, int C){
  __shared__ float t[32][33];
  const int tc = blockIdx.x * 32;
  const int tr = blockIdx.y * 32;
  const int j = threadIdx.x & 31, i0 = threadIdx.x >> 5;
  for(int ii = 0; ii < 4; ++ii){
    int r = i0 + ii * 8;
    t[r][j] = in[(size_t)(tr + r) * C + tc + j];
  }
  __syncthreads();
  for(int ii = 0; ii < 4; ++ii){
    int c = i0 + ii * 8;
    out[(size_t)(tc + c) * R + tr + j] = f2bf(t[j][c]);
  }
}

// ---------------- 2) down-proj + RMSNorm via MFMA ----------------
__global__ __launch_bounds__(256) void k_down_mfma(const float* __restrict__ x,
                                                   const uint16_t* __restrict__ wdt,
                                                   const float* __restrict__ rms_w,
                                                   uint16_t* __restrict__ h_out){
  __shared__ __align__(16) uint16_t as[32 * 64];
  __shared__ float hsq[32];
  const int tid  = threadIdx.x;
  const int wave = tid >> 6, lane = tid & 63;
  const int ml = lane & 15, qd = lane >> 4;
  const int m0 = blockIdx.x * 32;
  const int n0w = wave * 48;
  if(tid < 32) hsq[tid] = 0.f;

  f32x4 acc[2][3];
#pragma unroll
  for(int mt = 0; mt < 2; ++mt)
#pragma unroll
    for(int nt = 0; nt < 3; ++nt) acc[mt][nt] = fzero();

  const int srow = tid >> 3, sc = tid & 7;
  for(int kt = 0; kt < 16; ++kt){
    const float* src = x + (size_t)(m0 + srow) * 1024 + kt * 64 + sc * 8;
    float4 a = *reinterpret_cast<const float4*>(src);
    float4 b = *reinterpret_cast<const float4*>(src + 4);
    uint4 pk;
    pk.x = pack2(a.x, a.y); pk.y = pack2(a.z, a.w);
    pk.z = pack2(b.x, b.y); pk.w = pack2(b.z, b.w);
    __syncthreads();
    *reinterpret_cast<uint4*>(as + srow * 64 + ((sc ^ (srow & 7)) * 8)) = pk;
    __syncthreads();
#pragma unroll
    for(int kk = 0; kk < 2; ++kk){
      bf16x8 af[2];
#pragma unroll
      for(int mt = 0; mt < 2; ++mt){
        int row = mt * 16 + ml;
        af[mt] = load_frag(as + row * 64 + (((kk * 4 + qd) ^ (row & 7)) * 8));
      }
#pragma unroll
      for(int nt = 0; nt < 3; ++nt){
        bf16x8 bfr = load_frag(wdt + (size_t)(n0w + nt * 16 + ml) * 1024 + kt * 64 + kk * 32 + qd * 8);
#pragma unroll
        for(int mt = 0; mt < 2; ++mt)
          acc[mt][nt] = MFMA16x16(af[mt], bfr, acc[mt][nt]);
      }
    }
  }
  __syncthreads();
#pragma unroll
  for(int mt = 0; mt < 2; ++mt)
#pragma unroll
    for(int r = 0; r < 4; ++r){
      float s = acc[mt][0][r]*acc[mt][0][r] + acc[mt][1][r]*acc[mt][1][r] + acc[mt][2][r]*acc[mt][2][r];
#pragma unroll
      for(int off = 1; off < 16; off <<= 1) s += __shfl_xor(s, off);
      if(ml == 0) atomicAdd(&hsq[mt * 16 + qd * 4 + r], s);
    }
  __syncthreads();
  float rw[3];
#pragma unroll
  for(int nt = 0; nt < 3; ++nt) rw[nt] = rms_w[n0w + nt * 16 + ml];
#pragma unroll
  for(int mt = 0; mt < 2; ++mt)
#pragma unroll
    for(int r = 0; r < 4; ++r){
      int row = mt * 16 + qd * 4 + r;
      float scl = rsqrtf(hsq[row] * (1.0f / 192.0f) + 1e-6f);
#pragma unroll
      for(int nt = 0; nt < 3; ++nt)
        h_out[(size_t)(m0 + row) * 192 + n0w + nt * 16 + ml] = f2bf(acc[mt][nt][r] * scl * rw[nt]);
    }
}

// ---------------- 3) up-proj GEMM + fused RoPE + tile-swizzled scatter -------
// q_t/k_t global layout == attention LDS image:
//   [bh][kt][row=s&63][chunk c=d>>3 XOR (row&7)][d&7], elem granularity bf16
// v_t: [bh][kt][d][chunk c=(s&63)>>3 XOR (d&7)][s&7]
// Q additionally pre-scaled by 1/sqrt(192).
__global__ __launch_bounds__(256) void k_gemm_up(const uint16_t* __restrict__ hmat,
                                                 const uint16_t* __restrict__ wt,
                                                 uint16_t* __restrict__ q_t,
                                                 uint16_t* __restrict__ k_t,
                                                 uint16_t* __restrict__ v_t){
  const int wave = threadIdx.x >> 6, lane = threadIdx.x & 63;
  const int ml = lane & 15, qd = lane >> 4;
  const int m0 = blockIdx.y * 32;
  const int n0 = blockIdx.x * 256 + wave * 64;
  const int which = n0 / 3072;
  const int d0 = (n0 % 3072) >> 4;            // 4 consecutive d per wave, h = ml
  bf16x8 af[2][6];
#pragma unroll
  for(int mt = 0; mt < 2; ++mt)
#pragma unroll
    for(int kk = 0; kk < 6; ++kk)
      af[mt][kk] = load_frag(hmat + (size_t)(m0 + mt * 16 + ml) * 192 + kk * 32 + qd * 8);
  f32x4 acc[4][2];
#pragma unroll
  for(int nt = 0; nt < 4; ++nt){ acc[nt][0] = fzero(); acc[nt][1] = fzero(); }
#pragma unroll
  for(int nt = 0; nt < 4; ++nt){
#pragma unroll
    for(int kk = 0; kk < 6; ++kk){
      bf16x8 b = load_frag(wt + (size_t)(n0 + nt * 16 + ml) * 192 + kk * 32 + qd * 8);
      acc[nt][0] = MFMA16x16(af[0][kk], b, acc[nt][0]);
      acc[nt][1] = MFMA16x16(af[1][kk], b, acc[nt][1]);
    }
  }
  if(which < 2){
    uint16_t* dst = which ? k_t : q_t;
    const float qs = which ? 1.0f : 0.07216878364870322f;  // fold 1/sqrt(192) into Q
    const int c = d0 >> 3, sub = d0 & 7;                   // sub in {0,4}
#pragma unroll
    for(int mt = 0; mt < 2; ++mt)
#pragma unroll
      for(int r = 0; r < 4; ++r){
        int tok = m0 + mt * 16 + qd * 4 + r;
        int b = tok >> 11, s = tok & 2047;
        float v0 = acc[0][mt][r], v1 = acc[1][mt][r];
        float v2 = acc[2][mt][r], v3 = acc[3][mt][r];
        if(d0 >= 128 && d0 < 160){
#pragma unroll
          for(int p = 0; p < 2; ++p){
            int fi = (d0 + 2 * p - 128) >> 1;
            float invf = __expf(-(float)fi * 0.5756462732485114f); // ln(10000)/16
            float sn, cs;
            sincosf((float)s * invf, &sn, &cs);
            float e = p ? v2 : v0, o = p ? v3 : v1;
            float ne = e * cs - o * sn, no = o * cs + e * sn;
            if(p){ v2 = ne; v3 = no; } else { v0 = ne; v1 = no; }
          }
        }
        int kt2 = s >> 6, row = s & 63;
        uint2 pk; pk.x = pack2(v0 * qs, v1 * qs); pk.y = pack2(v2 * qs, v3 * qs);
        size_t off = ((size_t)(b * 16 + ml) * 32 + kt2) * (64 * 192)
                   + row * 192 + ((c ^ (row & 7)) * 8) + sub;
        *reinterpret_cast<uint2*>(dst + off) = pk;
      }
  } else {
#pragma unroll
    for(int mt = 0; mt < 2; ++mt){
      int tok0 = m0 + mt * 16 + qd * 4;
      int b = tok0 >> 11, s0 = tok0 & 2047;
      int kt2 = s0 >> 6, col = s0 & 63;
      int cc = col >> 3, sub = col & 7;                    // sub in {0,4}
#pragma unroll
      for(int nt = 0; nt < 4; ++nt){
        int d = d0 + nt;
        uint2 pk;
        pk.x = pack2(acc[nt][mt][0], acc[nt][mt][1]);
        pk.y = pack2(acc[nt][mt][2], acc[nt][mt][3]);
        size_t off = ((size_t)(b * 16 + ml) * 32 + kt2) * (192 * 64)
                   + d * 64 + ((cc ^ (d & 7)) * 8) + sub;
        *reinterpret_cast<uint2*>(v_t + off) = pk;
      }
    }
  }
}

// ---------------- 4) causal flash attention ----------------
// Tile-swizzled q_t/k_t/v_t (see k_gemm_up). 1D grid of 1024 blocks,
// XCD-grouped: bh = (L&7) + 8*(L>>8)  ->  each XCD owns 4 heads (K/V ~6.3MB, L2-resident).
// LDS: ks 24KB (K tile; P overlay after QK) + vs 26KB (V tile + 16 ones-rows) = 50KB -> 3 blocks/CU.
// No online max (|scores| <= ~1); row-sum l via ones-columns in V (o[12]).
__global__ __launch_bounds__(256, 3) void k_attn(const uint16_t* __restrict__ q_t,
                                                 const uint16_t* __restrict__ k_t,
                                                 const uint16_t* __restrict__ v_t,
                                                 uint16_t* __restrict__ attn_out){
  __shared__ __align__(16) uint16_t ks[64 * 192];
  __shared__ __align__(16) uint16_t vs[208 * 64];
  const int tid  = threadIdx.x;
  const int wave = tid >> 6;
  const int lane = tid & 63;
  const int ml   = lane & 15;
  const int qd   = lane >> 4;
  const int L    = blockIdx.x;
  const int idx  = L >> 3;
  const int qt   = 31 - (idx & 31);              // heavy q-tiles first per XCD
  const int bh   = (L & 7) + ((idx >> 5) << 3);

  // ones rows (192..207) of V -> row-sum accumulator column
  {
    uint32_t* vw = (uint32_t*)vs;
    vw[6144 + tid] = 0x3F803F80u;
    vw[6400 + tid] = 0x3F803F80u;
  }

  // stage Q tile (linear DMA: global layout == LDS image)
  {
    const uint16_t* qtile = q_t + ((size_t)bh * 32 + qt) * (64 * 192);
#pragma unroll
    for(int it = 0; it < 6; ++it){
      int seg = it * 4 + wave;
      gl2lds16(qtile + seg * 512 + lane * 8, ks + seg * 512);
    }
  }
  __syncthreads();
  bf16x8 qf[6];
  {
    int row = wave * 16 + ml;
#pragma unroll
    for(int kk = 0; kk < 6; ++kk)
      qf[kk] = load_frag(ks + row * 192 + (((kk * 4 + qd) ^ (row & 7)) * 8));
  }

  f32x4 o[13];
#pragma unroll
  for(int i = 0; i < 13; ++i) o[i] = fzero();

  for(int kt = 0; kt <= qt; ++kt){
    __syncthreads();                             // all reads of ks/vs complete
    const uint16_t* ktile = k_t + ((size_t)bh * 32 + kt) * (64 * 192);
    const uint16_t* vtile = v_t + ((size_t)bh * 32 + kt) * (192 * 64);
#pragma unroll
    for(int it = 0; it < 6; ++it){
      int seg = it * 4 + wave;
      gl2lds16(ktile + seg * 512 + lane * 8, ks + seg * 512);
    }
#pragma unroll
    for(int it = 0; it < 6; ++it){
      int seg = it * 4 + wave;
      gl2lds16(vtile + seg * 512 + lane * 8, vs + seg * 512);
    }
    __syncthreads();                             // DMA drained (vmcnt before barrier)

    // S = Q K^T, then exp (no max-subtract: scores are O(1))
    float p[4][4];
    const bool diag = (kt == qt);
#pragma unroll
    for(int nt = 0; nt < 4; ++nt){
      f32x4 a = fzero();
      int row = nt * 16 + ml;
#pragma unroll
      for(int kk = 0; kk < 6; ++kk){
        bf16x8 b = load_frag(ks + row * 192 + (((kk * 4 + qd) ^ (row & 7)) * 8));
        a = MFMA16x16(qf[kk], b, a);
      }
#pragma unroll
      for(int r = 0; r < 4; ++r){
        float v = a[r];
        if(diag){
          int i = qt * 64 + wave * 16 + qd * 4 + r;
          int j = kt * 64 + nt * 16 + ml;
          if(j > i) v = -1e9f;
        }
        p[nt][r] = __expf(v);
      }
    }

    __syncthreads();                             // QK reads of ks done -> P overlay
    uint16_t* psw = ks + wave * 1024;            // wave-private 16x64 P tile
#pragma unroll
    for(int nt = 0; nt < 4; ++nt)
#pragma unroll
      for(int r = 0; r < 4; ++r){
        int rp = qd * 4 + r;
        int col = nt * 16 + ml;
        int c = (col >> 3) ^ (rp & 7);
        psw[rp * 64 + c * 8 + (col & 7)] = f2bf(p[nt][r]);
      }
    // O += P V (13th d-tile = ones -> row-sum l in o[12])
#pragma unroll
    for(int kk2 = 0; kk2 < 2; ++kk2){
      int cp = (kk2 * 4 + qd) ^ (ml & 7);
      bf16x8 pa = load_frag(psw + ml * 64 + cp * 8);
#pragma unroll
      for(int dt = 0; dt < 13; ++dt){
        int row = dt * 16 + ml;
        int cv = (kk2 * 4 + qd) ^ (row & 7);
        bf16x8 vb = load_frag(vs + row * 64 + cv * 8);
        o[dt] = MFMA16x16(pa, vb, o[dt]);
      }
    }
  }

  const int hh = bh & 15, b = bh >> 4;
#pragma unroll
  for(int r = 0; r < 4; ++r){
    int i = qt * 64 + wave * 16 + qd * 4 + r;
    float inv = 1.0f / o[12][r];
    size_t obase = ((size_t)b * 2048 + i) * 3072 + hh * 192;
#pragma unroll
    for(int dt = 0; dt < 12; ++dt)
      attn_out[obase + dt * 16 + ml] = f2bf(o[dt][r] * inv);
  }
}

// ---------------- 5) out-proj GEMM (register MFMA, K=3072) ----------------
__global__ __launch_bounds__(256) void k_gemm_o(const uint16_t* __restrict__ a,
                                                const uint16_t* __restrict__ wt,
                                                float* __restrict__ out){
  const int wave = threadIdx.x >> 6, lane = threadIdx.x & 63;
  const int ml = lane & 15, qd = lane >> 4;
  const int m0 = blockIdx.y * 64 + (wave >> 1) * 32;
  const int n0 = blockIdx.x * 128 + (wave & 1) * 64;
  f32x4 acc[2][4];
#pragma unroll
  for(int mt = 0; mt < 2; ++mt)
#pragma unroll
    for(int nt = 0; nt < 4; ++nt) acc[mt][nt] = fzero();
  for(int kk = 0; kk < 96; ++kk){
    bf16x8 af[2], bfr[4];
#pragma unroll
    for(int mt = 0; mt < 2; ++mt)
      af[mt] = load_frag(a + (size_t)(m0 + mt * 16 + ml) * 3072 + kk * 32 + qd * 8);
#pragma unroll
    for(int nt = 0; nt < 4; ++nt)
      bfr[nt] = load_frag(wt + (size_t)(n0 + nt * 16 + ml) * 3072 + kk * 32 + qd * 8);
#pragma unroll
    for(int mt = 0; mt < 2; ++mt)
#pragma unroll
      for(int nt = 0; nt < 4; ++nt)
        acc[mt][nt] = MFMA16x16(af[mt], bfr[nt], acc[mt][nt]);
  }
#pragma unroll
  for(int mt = 0; mt < 2; ++mt)
#pragma unroll
    for(int nt = 0; nt < 4; ++nt)
#pragma unroll
      for(int r = 0; r < 4; ++r){
        int row = m0 + mt * 16 + qd * 4 + r;
        int col = n0 + nt * 16 + ml;
        out[(size_t)row * 1024 + col] = acc[mt][nt][r];
      }
}

// ---------------- launch ----------------

extern "C" void kernel_launch(void* const* d_in, const int* in_sizes, int n_in,
                              void* d_out, int out_size, void* d_ws, size_t ws_size,
                              hipStream_t stream) {
  (void)in_sizes; (void)n_in; (void)out_size; (void)ws_size;
  const float* x      = (const float*)d_in[0];
  const float* w_down = (const float*)d_in[2];
  const float* rms_w  = (const float*)d_in[3];
  const float* w_up   = (const float*)d_in[4];
  const float* w_o    = (const float*)d_in[5];
  float* out = (float*)d_out;

  char* ws = (char*)d_ws;
  uint16_t* h_bf   = (uint16_t*)(ws);                     // 1,572,864 B
  uint16_t* w_up_t = (uint16_t*)(ws + 1572864);           // 3,538,944 B
  uint16_t* w_o_t  = (uint16_t*)(ws + 5111808);           // 6,291,456 B
  uint16_t* w_dn_t = (uint16_t*)(ws + 11403264);          //   393,216 B
  uint16_t* q_tb   = (uint16_t*)(ws + 11796480);          // 25,165,824 B
  uint16_t* k_tb   = (uint16_t*)(ws + 36962304);          // 25,165,824 B
  uint16_t* v_tb   = (uint16_t*)(ws + 62128128);          // 25,165,824 B
  uint16_t* attnO  = (uint16_t*)(ws + 87293952);          // 25,165,824 B

  k_transpose_cvt<<<dim3(288, 6), 256, 0, stream>>>(w_up, w_up_t, 192, 9216);
  k_transpose_cvt<<<dim3(32, 96), 256, 0, stream>>>(w_o,  w_o_t,  3072, 1024);
  k_transpose_cvt<<<dim3(6, 32),  256, 0, stream>>>(w_down, w_dn_t, 1024, 192);
  k_down_mfma<<<128, 256, 0, stream>>>(x, w_dn_t, rms_w, h_bf);
  k_gemm_up<<<dim3(36, 128), 256, 0, stream>>>(h_bf, w_up_t, q_tb, k_tb, v_tb);
  k_attn<<<1024, 256, 0, stream>>>(q_tb, k_tb, v_tb, attnO);
  k_gemm_o<<<dim3(8, 64), 256, 0, stream>>>(attnO, w_o_t, out);
}

// Round 4
// 375.939 us; speedup vs baseline: 2.2540x; 1.2230x over previous
//
#include <hip/hip_runtime.h>
#include <stdint.h>
#include <stddef.h>

// ---------------- common helpers ----------------

typedef __bf16 bf16x8 __attribute__((ext_vector_type(8)));
typedef float  f32x4  __attribute__((ext_vector_type(4)));

#define MFMA16x16(a,b,c) __builtin_amdgcn_mfma_f32_16x16x32_bf16((a),(b),(c),0,0,0)

__device__ __forceinline__ uint16_t f2bf(float f){
  union { float f; uint32_t u; } v; v.f = f;
  uint32_t u = v.u + 0x7fffu + ((v.u >> 16) & 1u);
  return (uint16_t)(u >> 16);
}
__device__ __forceinline__ bf16x8 load_frag(const uint16_t* p){
  uint4 u = *reinterpret_cast<const uint4*>(p);
  return __builtin_bit_cast(bf16x8, u);
}
__device__ __forceinline__ f32x4 fzero(){
  f32x4 z = {0.f, 0.f, 0.f, 0.f};
  return z;
}
__device__ __forceinline__ uint32_t pack2(float a, float b){
  return (uint32_t)f2bf(a) | ((uint32_t)f2bf(b) << 16);
}
// async global->LDS DMA, 16B per lane, LDS dst = wave-uniform base + lane*16
__device__ __forceinline__ void gl2lds16(const uint16_t* g, uint16_t* l){
  __builtin_amdgcn_global_load_lds(
      (const __attribute__((address_space(1))) uint32_t*)g,
      (__attribute__((address_space(3))) uint32_t*)l,
      16, 0, 0);
}

// ---------------- 1) transpose + f32->bf16 convert ----------------
__global__ __launch_bounds__(256) void k_transpose_cvt(const float* __restrict__ in,
                                                       uint16_t* __restrict__ out,
                                                       int R, int C){
  __shared__ float t[32][33];
  const int tc = blockIdx.x * 32;
  const int tr = blockIdx.y * 32;
  const int j = threadIdx.x & 31, i0 = threadIdx.x >> 5;
  for(int ii = 0; ii < 4; ++ii){
    int r = i0 + ii * 8;
    t[r][j] = in[(size_t)(tr + r) * C + tc + j];
  }
  __syncthreads();
  for(int ii = 0; ii < 4; ++ii){
    int c = i0 + ii * 8;
    out[(size_t)(tc + c) * R + tr + j] = f2bf(t[j][c]);
  }
}

// ---------------- 2) down-proj + RMSNorm via MFMA ----------------
__global__ __launch_bounds__(256) void k_down_mfma(const float* __restrict__ x,
                                                   const uint16_t* __restrict__ wdt,
                                                   const float* __restrict__ rms_w,
                                                   uint16_t* __restrict__ h_out){
  __shared__ __align__(16) uint16_t as[32 * 64];
  __shared__ float hsq[32];
  const int tid  = threadIdx.x;
  const int wave = tid >> 6, lane = tid & 63;
  const int ml = lane & 15, qd = lane >> 4;
  const int m0 = blockIdx.x * 32;
  const int n0w = wave * 48;
  if(tid < 32) hsq[tid] = 0.f;

  f32x4 acc[2][3];
#pragma unroll
  for(int mt = 0; mt < 2; ++mt)
#pragma unroll
    for(int nt = 0; nt < 3; ++nt) acc[mt][nt] = fzero();

  const int srow = tid >> 3, sc = tid & 7;
  for(int kt = 0; kt < 16; ++kt){
    const float* src = x + (size_t)(m0 + srow) * 1024 + kt * 64 + sc * 8;
    float4 a = *reinterpret_cast<const float4*>(src);
    float4 b = *reinterpret_cast<const float4*>(src + 4);
    uint4 pk;
    pk.x = pack2(a.x, a.y); pk.y = pack2(a.z, a.w);
    pk.z = pack2(b.x, b.y); pk.w = pack2(b.z, b.w);
    __syncthreads();
    *reinterpret_cast<uint4*>(as + srow * 64 + ((sc ^ (srow & 7)) * 8)) = pk;
    __syncthreads();
#pragma unroll
    for(int kk = 0; kk < 2; ++kk){
      bf16x8 af[2];
#pragma unroll
      for(int mt = 0; mt < 2; ++mt){
        int row = mt * 16 + ml;
        af[mt] = load_frag(as + row * 64 + (((kk * 4 + qd) ^ (row & 7)) * 8));
      }
#pragma unroll
      for(int nt = 0; nt < 3; ++nt){
        bf16x8 bfr = load_frag(wdt + (size_t)(n0w + nt * 16 + ml) * 1024 + kt * 64 + kk * 32 + qd * 8);
#pragma unroll
        for(int mt = 0; mt < 2; ++mt)
          acc[mt][nt] = MFMA16x16(af[mt], bfr, acc[mt][nt]);
      }
    }
  }
  __syncthreads();
#pragma unroll
  for(int mt = 0; mt < 2; ++mt)
#pragma unroll
    for(int r = 0; r < 4; ++r){
      float s = acc[mt][0][r]*acc[mt][0][r] + acc[mt][1][r]*acc[mt][1][r] + acc[mt][2][r]*acc[mt][2][r];
#pragma unroll
      for(int off = 1; off < 16; off <<= 1) s += __shfl_xor(s, off);
      if(ml == 0) atomicAdd(&hsq[mt * 16 + qd * 4 + r], s);
    }
  __syncthreads();
  float rw[3];
#pragma unroll
  for(int nt = 0; nt < 3; ++nt) rw[nt] = rms_w[n0w + nt * 16 + ml];
#pragma unroll
  for(int mt = 0; mt < 2; ++mt)
#pragma unroll
    for(int r = 0; r < 4; ++r){
      int row = mt * 16 + qd * 4 + r;
      float scl = rsqrtf(hsq[row] * (1.0f / 192.0f) + 1e-6f);
#pragma unroll
      for(int nt = 0; nt < 3; ++nt)
        h_out[(size_t)(m0 + row) * 192 + n0w + nt * 16 + ml] = f2bf(acc[mt][nt][r] * scl * rw[nt]);
    }
}

// ---------------- 3) up-proj GEMM + fused RoPE + tile-swizzled scatter -------
__global__ __launch_bounds__(256) void k_gemm_up(const uint16_t* __restrict__ hmat,
                                                 const uint16_t* __restrict__ wt,
                                                 uint16_t* __restrict__ q_t,
                                                 uint16_t* __restrict__ k_t,
                                                 uint16_t* __restrict__ v_t){
  const int wave = threadIdx.x >> 6, lane = threadIdx.x & 63;
  const int ml = lane & 15, qd = lane >> 4;
  const int m0 = blockIdx.y * 32;
  const int n0 = blockIdx.x * 256 + wave * 64;
  const int which = n0 / 3072;
  const int d0 = (n0 % 3072) >> 4;            // 4 consecutive d per wave, h = ml
  bf16x8 af[2][6];
#pragma unroll
  for(int mt = 0; mt < 2; ++mt)
#pragma unroll
    for(int kk = 0; kk < 6; ++kk)
      af[mt][kk] = load_frag(hmat + (size_t)(m0 + mt * 16 + ml) * 192 + kk * 32 + qd * 8);
  f32x4 acc[4][2];
#pragma unroll
  for(int nt = 0; nt < 4; ++nt){ acc[nt][0] = fzero(); acc[nt][1] = fzero(); }
#pragma unroll
  for(int nt = 0; nt < 4; ++nt){
#pragma unroll
    for(int kk = 0; kk < 6; ++kk){
      bf16x8 b = load_frag(wt + (size_t)(n0 + nt * 16 + ml) * 192 + kk * 32 + qd * 8);
      acc[nt][0] = MFMA16x16(af[0][kk], b, acc[nt][0]);
      acc[nt][1] = MFMA16x16(af[1][kk], b, acc[nt][1]);
    }
  }
  if(which < 2){
    uint16_t* dst = which ? k_t : q_t;
    const float qs = which ? 1.0f : 0.07216878364870322f;  // fold 1/sqrt(192) into Q
    const int c = d0 >> 3, sub = d0 & 7;                   // sub in {0,4}
#pragma unroll
    for(int mt = 0; mt < 2; ++mt)
#pragma unroll
      for(int r = 0; r < 4; ++r){
        int tok = m0 + mt * 16 + qd * 4 + r;
        int b = tok >> 11, s = tok & 2047;
        float v0 = acc[0][mt][r], v1 = acc[1][mt][r];
        float v2 = acc[2][mt][r], v3 = acc[3][mt][r];
        if(d0 >= 128 && d0 < 160){
#pragma unroll
          for(int p = 0; p < 2; ++p){
            int fi = (d0 + 2 * p - 128) >> 1;
            float invf = __expf(-(float)fi * 0.5756462732485114f); // ln(10000)/16
            float sn, cs;
            sincosf((float)s * invf, &sn, &cs);
            float e = p ? v2 : v0, o = p ? v3 : v1;
            float ne = e * cs - o * sn, no = o * cs + e * sn;
            if(p){ v2 = ne; v3 = no; } else { v0 = ne; v1 = no; }
          }
        }
        int kt2 = s >> 6, row = s & 63;
        uint2 pk; pk.x = pack2(v0 * qs, v1 * qs); pk.y = pack2(v2 * qs, v3 * qs);
        size_t off = ((size_t)(b * 16 + ml) * 32 + kt2) * (64 * 192)
                   + row * 192 + ((c ^ (row & 7)) * 8) + sub;
        *reinterpret_cast<uint2*>(dst + off) = pk;
      }
  } else {
#pragma unroll
    for(int mt = 0; mt < 2; ++mt){
      int tok0 = m0 + mt * 16 + qd * 4;
      int b = tok0 >> 11, s0 = tok0 & 2047;
      int kt2 = s0 >> 6, col = s0 & 63;
      int cc = col >> 3, sub = col & 7;
#pragma unroll
      for(int nt = 0; nt < 4; ++nt){
        int d = d0 + nt;
        uint2 pk;
        pk.x = pack2(acc[nt][mt][0], acc[nt][mt][1]);
        pk.y = pack2(acc[nt][mt][2], acc[nt][mt][3]);
        size_t off = ((size_t)(b * 16 + ml) * 32 + kt2) * (192 * 64)
                   + d * 64 + ((cc ^ (d & 7)) * 8) + sub;
        *reinterpret_cast<uint2*>(v_t + off) = pk;
      }
    }
  }
}

// ---------------- 4) causal flash attention ----------------
__global__ __launch_bounds__(256, 3) void k_attn(const uint16_t* __restrict__ q_t,
                                                 const uint16_t* __restrict__ k_t,
                                                 const uint16_t* __restrict__ v_t,
                                                 uint16_t* __restrict__ attn_out){
  __shared__ __align__(16) uint16_t ks[64 * 192];
  __shared__ __align__(16) uint16_t vs[208 * 64];
  const int tid  = threadIdx.x;
  const int wave = tid >> 6;
  const int lane = tid & 63;
  const int ml   = lane & 15;
  const int qd   = lane >> 4;
  const int L    = blockIdx.x;
  const int idx  = L >> 3;
  const int qt   = 31 - (idx & 31);
  const int bh   = (L & 7) + ((idx >> 5) << 3);

  {
    uint32_t* vw = (uint32_t*)vs;
    vw[6144 + tid] = 0x3F803F80u;
    vw[6400 + tid] = 0x3F803F80u;
  }

  {
    const uint16_t* qtile = q_t + ((size_t)bh * 32 + qt) * (64 * 192);
#pragma unroll
    for(int it = 0; it < 6; ++it){
      int seg = it * 4 + wave;
      gl2lds16(qtile + seg * 512 + lane * 8, ks + seg * 512);
    }
  }
  __syncthreads();
  bf16x8 qf[6];
  {
    int row = wave * 16 + ml;
#pragma unroll
    for(int kk = 0; kk < 6; ++kk)
      qf[kk] = load_frag(ks + row * 192 + (((kk * 4 + qd) ^ (row & 7)) * 8));
  }

  f32x4 o[13];
#pragma unroll
  for(int i = 0; i < 13; ++i) o[i] = fzero();

  for(int kt = 0; kt <= qt; ++kt){
    __syncthreads();
    const uint16_t* ktile = k_t + ((size_t)bh * 32 + kt) * (64 * 192);
    const uint16_t* vtile = v_t + ((size_t)bh * 32 + kt) * (192 * 64);
#pragma unroll
    for(int it = 0; it < 6; ++it){
      int seg = it * 4 + wave;
      gl2lds16(ktile + seg * 512 + lane * 8, ks + seg * 512);
    }
#pragma unroll
    for(int it = 0; it < 6; ++it){
      int seg = it * 4 + wave;
      gl2lds16(vtile + seg * 512 + lane * 8, vs + seg * 512);
    }
    __syncthreads();

    float p[4][4];
    const bool diag = (kt == qt);
#pragma unroll
    for(int nt = 0; nt < 4; ++nt){
      f32x4 a = fzero();
      int row = nt * 16 + ml;
#pragma unroll
      for(int kk = 0; kk < 6; ++kk){
        bf16x8 b = load_frag(ks + row * 192 + (((kk * 4 + qd) ^ (row & 7)) * 8));
        a = MFMA16x16(qf[kk], b, a);
      }
#pragma unroll
      for(int r = 0; r < 4; ++r){
        float v = a[r];
        if(diag){
          int i = qt * 64 + wave * 16 + qd * 4 + r;
          int j = kt * 64 + nt * 16 + ml;
          if(j > i) v = -1e9f;
        }
        p[nt][r] = __expf(v);
      }
    }

    __syncthreads();
    uint16_t* psw = ks + wave * 1024;
#pragma unroll
    for(int nt = 0; nt < 4; ++nt)
#pragma unroll
      for(int r = 0; r < 4; ++r){
        int rp = qd * 4 + r;
        int col = nt * 16 + ml;
        int c = (col >> 3) ^ (rp & 7);
        psw[rp * 64 + c * 8 + (col & 7)] = f2bf(p[nt][r]);
      }
#pragma unroll
    for(int kk2 = 0; kk2 < 2; ++kk2){
      int cp = (kk2 * 4 + qd) ^ (ml & 7);
      bf16x8 pa = load_frag(psw + ml * 64 + cp * 8);
#pragma unroll
      for(int dt = 0; dt < 13; ++dt){
        int row = dt * 16 + ml;
        int cv = (kk2 * 4 + qd) ^ (row & 7);
        bf16x8 vb = load_frag(vs + row * 64 + cv * 8);
        o[dt] = MFMA16x16(pa, vb, o[dt]);
      }
    }
  }

  const int hh = bh & 15, b = bh >> 4;
#pragma unroll
  for(int r = 0; r < 4; ++r){
    int i = qt * 64 + wave * 16 + qd * 4 + r;
    float inv = 1.0f / o[12][r];
    size_t obase = ((size_t)b * 2048 + i) * 3072 + hh * 192;
#pragma unroll
    for(int dt = 0; dt < 12; ++dt)
      attn_out[obase + dt * 16 + ml] = f2bf(o[dt][r] * inv);
  }
}

// ---------------- 5) out-proj GEMM: m97-style LDS-tiled, split-K=2 ----------
// a: [4096][3072] bf16, wt: [1024][3072] bf16 (w_o^T)
// part: [2][4096][1024] f32 partials.  grid (8 n, 32 m, 2 kz), block 256.
// Tile 128m x 128n x BK64; LDS image XOR-swizzled via global-address permute;
// staging via global_load_lds dwordx4 (8 DMA/wave/iter).
__global__ __launch_bounds__(256) void k_gemm_o_tile(const uint16_t* __restrict__ a,
                                                     const uint16_t* __restrict__ wt,
                                                     float* __restrict__ part){
  __shared__ __align__(16) uint16_t as[128 * 64];
  __shared__ __align__(16) uint16_t bs[128 * 64];
  const int wave = threadIdx.x >> 6, lane = threadIdx.x & 63;
  const int ml = lane & 15, qd = lane >> 4;
  const int m0 = blockIdx.y * 128, n0 = blockIdx.x * 128;
  const int kz = blockIdx.z;
  const int mo = (wave >> 1) * 64, no = (wave & 1) * 64;

  // per-lane DMA source pattern: row within 8-row segment + XOR-permuted chunk
  const int lrow = lane >> 3;
  const int gch  = (lane & 7) ^ (lrow & 7);
  const uint16_t* abase = a  + (size_t)(m0 + lrow) * 3072 + kz * 1536 + gch * 8;
  const uint16_t* bbase = wt + (size_t)(n0 + lrow) * 3072 + kz * 1536 + gch * 8;

  f32x4 acc[4][4];
#pragma unroll
  for(int mt = 0; mt < 4; ++mt)
#pragma unroll
    for(int nt = 0; nt < 4; ++nt) acc[mt][nt] = fzero();

  for(int kt = 0; kt < 24; ++kt){
    __syncthreads();                       // prior reads of as/bs done
#pragma unroll
    for(int it = 0; it < 4; ++it){
      int seg = it * 4 + wave;             // 8-row group, 0..15
      gl2lds16(abase + (size_t)seg * 24576 + kt * 64, as + seg * 512);
      gl2lds16(bbase + (size_t)seg * 24576 + kt * 64, bs + seg * 512);
    }
    __syncthreads();                       // DMA drained
#pragma unroll
    for(int ks2 = 0; ks2 < 2; ++ks2){
      bf16x8 af[4], bfr[4];
#pragma unroll
      for(int mt = 0; mt < 4; ++mt){
        int row = mo + mt * 16 + ml;
        af[mt] = load_frag(as + row * 64 + (((ks2 * 4 + qd) ^ (row & 7)) * 8));
      }
#pragma unroll
      for(int nt = 0; nt < 4; ++nt){
        int row = no + nt * 16 + ml;
        bfr[nt] = load_frag(bs + row * 64 + (((ks2 * 4 + qd) ^ (row & 7)) * 8));
      }
#pragma unroll
      for(int mt = 0; mt < 4; ++mt)
#pragma unroll
        for(int nt = 0; nt < 4; ++nt)
          acc[mt][nt] = MFMA16x16(af[mt], bfr[nt], acc[mt][nt]);
    }
  }

  float* dst = part + (size_t)kz * 4096 * 1024;
#pragma unroll
  for(int mt = 0; mt < 4; ++mt)
#pragma unroll
    for(int nt = 0; nt < 4; ++nt)
#pragma unroll
      for(int r = 0; r < 4; ++r){
        int row = m0 + mo + mt * 16 + qd * 4 + r;
        int col = n0 + no + nt * 16 + ml;
        dst[(size_t)row * 1024 + col] = acc[mt][nt][r];
      }
}

// out = part0 + part1 (float4)
__global__ __launch_bounds__(256) void k_addout(const float* __restrict__ part,
                                                float* __restrict__ out){
  int i = blockIdx.x * 256 + threadIdx.x;
  const float4* p0 = (const float4*)part;
  const float4* p1 = p0 + (size_t)1048576;
  float4 a = p0[i], b = p1[i];
  float4 c; c.x = a.x + b.x; c.y = a.y + b.y; c.z = a.z + b.z; c.w = a.w + b.w;
  ((float4*)out)[i] = c;
}

// ---------------- launch ----------------

extern "C" void kernel_launch(void* const* d_in, const int* in_sizes, int n_in,
                              void* d_out, int out_size, void* d_ws, size_t ws_size,
                              hipStream_t stream) {
  (void)in_sizes; (void)n_in; (void)out_size; (void)ws_size;
  const float* x      = (const float*)d_in[0];
  const float* w_down = (const float*)d_in[2];
  const float* rms_w  = (const float*)d_in[3];
  const float* w_up   = (const float*)d_in[4];
  const float* w_o    = (const float*)d_in[5];
  float* out = (float*)d_out;

  char* ws = (char*)d_ws;
  uint16_t* h_bf   = (uint16_t*)(ws);                     // 1,572,864 B
  uint16_t* w_up_t = (uint16_t*)(ws + 1572864);           // 3,538,944 B
  uint16_t* w_o_t  = (uint16_t*)(ws + 5111808);           // 6,291,456 B
  uint16_t* w_dn_t = (uint16_t*)(ws + 11403264);          //   393,216 B
  uint16_t* q_tb   = (uint16_t*)(ws + 11796480);          // 25,165,824 B
  uint16_t* k_tb   = (uint16_t*)(ws + 36962304);          // 25,165,824 B
  uint16_t* v_tb   = (uint16_t*)(ws + 62128128);          // 25,165,824 B
  uint16_t* attnO  = (uint16_t*)(ws + 87293952);          // 25,165,824 B
  float*    part   = (float*)(ws + 11796480);             // alias q_tb/k_tb (dead after attn): 33,554,432 B

  k_transpose_cvt<<<dim3(288, 6), 256, 0, stream>>>(w_up, w_up_t, 192, 9216);
  k_transpose_cvt<<<dim3(32, 96), 256, 0, stream>>>(w_o,  w_o_t,  3072, 1024);
  k_transpose_cvt<<<dim3(6, 32),  256, 0, stream>>>(w_down, w_dn_t, 1024, 192);
  k_down_mfma<<<128, 256, 0, stream>>>(x, w_dn_t, rms_w, h_bf);
  k_gemm_up<<<dim3(36, 128), 256, 0, stream>>>(h_bf, w_up_t, q_tb, k_tb, v_tb);
  k_attn<<<1024, 256, 0, stream>>>(q_tb, k_tb, v_tb, attnO);
  k_gemm_o_tile<<<dim3(8, 32, 2), 256, 0, stream>>>(attnO, w_o_t, part);
  k_addout<<<4096, 256, 0, stream>>>(part, out);
}

// Round 5
// 354.385 us; speedup vs baseline: 2.3911x; 1.0608x over previous
//
#include <hip/hip_runtime.h>
#include <stdint.h>
#include <stddef.h>

// ---------------- common helpers ----------------

typedef __bf16 bf16x8 __attribute__((ext_vector_type(8)));
typedef float  f32x4  __attribute__((ext_vector_type(4)));

#define MFMA16x16(a,b,c) __builtin_amdgcn_mfma_f32_16x16x32_bf16((a),(b),(c),0,0,0)

__device__ __forceinline__ uint16_t f2bf(float f){
  union { float f; uint32_t u; } v; v.f = f;
  uint32_t u = v.u + 0x7fffu + ((v.u >> 16) & 1u);
  return (uint16_t)(u >> 16);
}
__device__ __forceinline__ bf16x8 load_frag(const uint16_t* p){
  uint4 u = *reinterpret_cast<const uint4*>(p);
  return __builtin_bit_cast(bf16x8, u);
}
__device__ __forceinline__ f32x4 fzero(){
  f32x4 z = {0.f, 0.f, 0.f, 0.f};
  return z;
}
__device__ __forceinline__ uint32_t pack2(float a, float b){
  return (uint32_t)f2bf(a) | ((uint32_t)f2bf(b) << 16);
}
// async global->LDS DMA, 16B per lane, LDS dst = wave-uniform base + lane*16
__device__ __forceinline__ void gl2lds16(const uint16_t* g, uint16_t* l){
  __builtin_amdgcn_global_load_lds(
      (const __attribute__((address_space(1))) uint32_t*)g,
      (__attribute__((address_space(3))) uint32_t*)l,
      16, 0, 0);
}

// ---------------- 1) transpose + f32->bf16 convert ----------------
__global__ __launch_bounds__(256) void k_transpose_cvt(const float* __restrict__ in,
                                                       uint16_t* __restrict__ out,
                                                       int R, int C){
  __shared__ float t[32][33];
  const int tc = blockIdx.x * 32;
  const int tr = blockIdx.y * 32;
  const int j = threadIdx.x & 31, i0 = threadIdx.x >> 5;
  for(int ii = 0; ii < 4; ++ii){
    int r = i0 + ii * 8;
    t[r][j] = in[(size_t)(tr + r) * C + tc + j];
  }
  __syncthreads();
  for(int ii = 0; ii < 4; ++ii){
    int c = i0 + ii * 8;
    out[(size_t)(tc + c) * R + tr + j] = f2bf(t[j][c]);
  }
}

// ---------------- 2) down-proj + RMSNorm via MFMA ----------------
__global__ __launch_bounds__(256) void k_down_mfma(const float* __restrict__ x,
                                                   const uint16_t* __restrict__ wdt,
                                                   const float* __restrict__ rms_w,
                                                   uint16_t* __restrict__ h_out){
  __shared__ __align__(16) uint16_t as[32 * 64];
  __shared__ float hsq[32];
  const int tid  = threadIdx.x;
  const int wave = tid >> 6, lane = tid & 63;
  const int ml = lane & 15, qd = lane >> 4;
  const int m0 = blockIdx.x * 32;
  const int n0w = wave * 48;
  if(tid < 32) hsq[tid] = 0.f;

  f32x4 acc[2][3];
#pragma unroll
  for(int mt = 0; mt < 2; ++mt)
#pragma unroll
    for(int nt = 0; nt < 3; ++nt) acc[mt][nt] = fzero();

  const int srow = tid >> 3, sc = tid & 7;
  for(int kt = 0; kt < 16; ++kt){
    const float* src = x + (size_t)(m0 + srow) * 1024 + kt * 64 + sc * 8;
    float4 a = *reinterpret_cast<const float4*>(src);
    float4 b = *reinterpret_cast<const float4*>(src + 4);
    uint4 pk;
    pk.x = pack2(a.x, a.y); pk.y = pack2(a.z, a.w);
    pk.z = pack2(b.x, b.y); pk.w = pack2(b.z, b.w);
    __syncthreads();
    *reinterpret_cast<uint4*>(as + srow * 64 + ((sc ^ (srow & 7)) * 8)) = pk;
    __syncthreads();
#pragma unroll
    for(int kk = 0; kk < 2; ++kk){
      bf16x8 af[2];
#pragma unroll
      for(int mt = 0; mt < 2; ++mt){
        int row = mt * 16 + ml;
        af[mt] = load_frag(as + row * 64 + (((kk * 4 + qd) ^ (row & 7)) * 8));
      }
#pragma unroll
      for(int nt = 0; nt < 3; ++nt){
        bf16x8 bfr = load_frag(wdt + (size_t)(n0w + nt * 16 + ml) * 1024 + kt * 64 + kk * 32 + qd * 8);
#pragma unroll
        for(int mt = 0; mt < 2; ++mt)
          acc[mt][nt] = MFMA16x16(af[mt], bfr, acc[mt][nt]);
      }
    }
  }
  __syncthreads();
#pragma unroll
  for(int mt = 0; mt < 2; ++mt)
#pragma unroll
    for(int r = 0; r < 4; ++r){
      float s = acc[mt][0][r]*acc[mt][0][r] + acc[mt][1][r]*acc[mt][1][r] + acc[mt][2][r]*acc[mt][2][r];
#pragma unroll
      for(int off = 1; off < 16; off <<= 1) s += __shfl_xor(s, off);
      if(ml == 0) atomicAdd(&hsq[mt * 16 + qd * 4 + r], s);
    }
  __syncthreads();
  float rw[3];
#pragma unroll
  for(int nt = 0; nt < 3; ++nt) rw[nt] = rms_w[n0w + nt * 16 + ml];
#pragma unroll
  for(int mt = 0; mt < 2; ++mt)
#pragma unroll
    for(int r = 0; r < 4; ++r){
      int row = mt * 16 + qd * 4 + r;
      float scl = rsqrtf(hsq[row] * (1.0f / 192.0f) + 1e-6f);
#pragma unroll
      for(int nt = 0; nt < 3; ++nt)
        h_out[(size_t)(m0 + row) * 192 + n0w + nt * 16 + ml] = f2bf(acc[mt][nt][r] * scl * rw[nt]);
    }
}

// ---------------- 3) up-proj GEMM v2: LDS repack -> full-line stores --------
// Block: 32m x 512n (= 32 d x 16 h, single `which`), grid (18, 128), 4 waves.
// Wave: 32m x 128n = 8 consecutive d (chunk jw = wave) x 16 h (= ml).
// Target image (consumed by k_attn DMA): q/k tile: row*192 + ((c^(row&7))*8)+e;
// v tile: d*64 + ((cs^(d&7))*8)+e.  The 32-d block span maps per row onto one
// full 64B line: (cb|jg)^rs = (cb^(rs&4)) + (jg^(rs&3)).  Repack via 33KB LDS
// ([h][129 slots][8], padded: +1 slot/h -> <=2-way banks), then dwordx4 stores
// covering 16 full lines per instruction.
__global__ __launch_bounds__(256) void k_gemm_up(const uint16_t* __restrict__ hmat,
                                                 const uint16_t* __restrict__ wt,
                                                 uint16_t* __restrict__ q_t,
                                                 uint16_t* __restrict__ k_t,
                                                 uint16_t* __restrict__ v_t){
  __shared__ __align__(16) uint16_t rp[16 * 129 * 8];   // 33,024 B
  const int wave = threadIdx.x >> 6, lane = threadIdx.x & 63;
  const int ml = lane & 15, qd = lane >> 4;
  const int m0 = blockIdx.y * 32;
  const int bx = blockIdx.x;
  const int which = bx / 6;                // 0=q 1=k 2=v
  const int d0b = (bx % 6) * 32;
  const int n0w = bx * 512 + wave * 128;
  const int d0w = d0b + wave * 8;

  bf16x8 af[2][6];
#pragma unroll
  for(int mt = 0; mt < 2; ++mt)
#pragma unroll
    for(int kk = 0; kk < 6; ++kk)
      af[mt][kk] = load_frag(hmat + (size_t)(m0 + mt * 16 + ml) * 192 + kk * 32 + qd * 8);

  f32x4 acc[8][2];
#pragma unroll
  for(int nt = 0; nt < 8; ++nt){ acc[nt][0] = fzero(); acc[nt][1] = fzero(); }
#pragma unroll
  for(int nt = 0; nt < 8; ++nt){
#pragma unroll
    for(int kk = 0; kk < 6; ++kk){
      bf16x8 b = load_frag(wt + (size_t)(n0w + nt * 16 + ml) * 192 + kk * 32 + qd * 8);
      acc[nt][0] = MFMA16x16(af[0][kk], b, acc[nt][0]);
      acc[nt][1] = MFMA16x16(af[1][kk], b, acc[nt][1]);
    }
  }

  const int b   = m0 >> 11;
  const int s0  = m0 & 2047;
  const int kt2 = s0 >> 6;
  const int row0 = s0 & 63;                // 32-aligned: rs bits come from t
  uint4* rp4 = (uint4*)rp;

  if(which < 2){
    const float qs = which ? 1.0f : 0.07216878364870322f;   // fold 1/sqrt(192) into Q
    const bool rope = (d0w >= 128) && (d0w < 160);
#pragma unroll
    for(int mt = 0; mt < 2; ++mt)
#pragma unroll
      for(int r = 0; r < 4; ++r){
        int t = mt * 16 + qd * 4 + r;
        int s = s0 + t;
        float v[8];
#pragma unroll
        for(int nt = 0; nt < 8; ++nt) v[nt] = acc[nt][mt][r] * qs;
        if(rope){
#pragma unroll
          for(int pi = 0; pi < 4; ++pi){
            int fi = (d0w + 2 * pi - 128) >> 1;
            float invf = __expf(-(float)fi * 0.5756462732485114f); // ln(10000)/16
            float sn, cs;
            sincosf((float)s * invf, &sn, &cs);
            float e = v[2 * pi], o = v[2 * pi + 1];
            v[2 * pi]     = e * cs - o * sn;
            v[2 * pi + 1] = o * cs + e * sn;
          }
        }
        uint4 pk;
        pk.x = pack2(v[0], v[1]); pk.y = pack2(v[2], v[3]);
        pk.z = pack2(v[4], v[5]); pk.w = pack2(v[6], v[7]);
        rp4[ml * 129 + t * 4 + (wave ^ (t & 3))] = pk;
      }
  } else {
#pragma unroll
    for(int nt = 0; nt < 8; ++nt){
      int dl = wave * 8 + nt;
#pragma unroll
      for(int mt = 0; mt < 2; ++mt){
        int jc = mt * 2 + (qd >> 1);
        int slot = ml * 129 + dl * 4 + (jc ^ (dl & 3));
        uint2 pk;
        pk.x = pack2(acc[nt][mt][0], acc[nt][mt][1]);
        pk.y = pack2(acc[nt][mt][2], acc[nt][mt][3]);
        *(reinterpret_cast<uint2*>(rp + slot * 8) + (qd & 1)) = pk;
      }
    }
  }
  __syncthreads();

  if(which < 2){
    uint16_t* dst = which ? k_t : q_t;
    const int cb = d0b >> 3;
#pragma unroll
    for(int it = 0; it < 8; ++it){
      int h = wave * 4 + (it & 3), rhalf = it >> 2;
      int tloc = rhalf * 16 + (lane >> 2), p = lane & 3;
      int row = row0 + tloc;
      uint4 val = rp4[h * 129 + tloc * 4 + p];
      size_t off = ((size_t)(b * 16 + h) * 32 + kt2) * 12288
                 + (size_t)row * 192 + ((cb ^ (tloc & 4)) + p) * 8;
      *reinterpret_cast<uint4*>(dst + off) = val;
    }
  } else {
    const int cs0 = row0 >> 3;
#pragma unroll
    for(int it = 0; it < 8; ++it){
      int h = wave * 4 + (it & 3), dhalf = it >> 2;
      int dl = dhalf * 16 + (lane >> 2), p = lane & 3;
      uint4 val = rp4[h * 129 + dl * 4 + p];
      size_t off = ((size_t)(b * 16 + h) * 32 + kt2) * 12288
                 + (size_t)(d0b + dl) * 64 + ((cs0 ^ (dl & 4)) + p) * 8;
      *reinterpret_cast<uint4*>(v_t + off) = val;
    }
  }
}

// ---------------- 4) causal flash attention ----------------
__global__ __launch_bounds__(256, 3) void k_attn(const uint16_t* __restrict__ q_t,
                                                 const uint16_t* __restrict__ k_t,
                                                 const uint16_t* __restrict__ v_t,
                                                 uint16_t* __restrict__ attn_out){
  __shared__ __align__(16) uint16_t ks[64 * 192];
  __shared__ __align__(16) uint16_t vs[208 * 64];
  const int tid  = threadIdx.x;
  const int wave = tid >> 6;
  const int lane = tid & 63;
  const int ml   = lane & 15;
  const int qd   = lane >> 4;
  const int L    = blockIdx.x;
  const int idx  = L >> 3;
  const int qt   = 31 - (idx & 31);
  const int bh   = (L & 7) + ((idx >> 5) << 3);

  {
    uint32_t* vw = (uint32_t*)vs;
    vw[6144 + tid] = 0x3F803F80u;
    vw[6400 + tid] = 0x3F803F80u;
  }

  {
    const uint16_t* qtile = q_t + ((size_t)bh * 32 + qt) * (64 * 192);
#pragma unroll
    for(int it = 0; it < 6; ++it){
      int seg = it * 4 + wave;
      gl2lds16(qtile + seg * 512 + lane * 8, ks + seg * 512);
    }
  }
  __syncthreads();
  bf16x8 qf[6];
  {
    int row = wave * 16 + ml;
#pragma unroll
    for(int kk = 0; kk < 6; ++kk)
      qf[kk] = load_frag(ks + row * 192 + (((kk * 4 + qd) ^ (row & 7)) * 8));
  }

  f32x4 o[13];
#pragma unroll
  for(int i = 0; i < 13; ++i) o[i] = fzero();

  for(int kt = 0; kt <= qt; ++kt){
    __syncthreads();
    const uint16_t* ktile = k_t + ((size_t)bh * 32 + kt) * (64 * 192);
    const uint16_t* vtile = v_t + ((size_t)bh * 32 + kt) * (192 * 64);
#pragma unroll
    for(int it = 0; it < 6; ++it){
      int seg = it * 4 + wave;
      gl2lds16(ktile + seg * 512 + lane * 8, ks + seg * 512);
    }
#pragma unroll
    for(int it = 0; it < 6; ++it){
      int seg = it * 4 + wave;
      gl2lds16(vtile + seg * 512 + lane * 8, vs + seg * 512);
    }
    __syncthreads();

    float p[4][4];
    const bool diag = (kt == qt);
#pragma unroll
    for(int nt = 0; nt < 4; ++nt){
      f32x4 a = fzero();
      int row = nt * 16 + ml;
#pragma unroll
      for(int kk = 0; kk < 6; ++kk){
        bf16x8 b = load_frag(ks + row * 192 + (((kk * 4 + qd) ^ (row & 7)) * 8));
        a = MFMA16x16(qf[kk], b, a);
      }
#pragma unroll
      for(int r = 0; r < 4; ++r){
        float v = a[r];
        if(diag){
          int i = qt * 64 + wave * 16 + qd * 4 + r;
          int j = kt * 64 + nt * 16 + ml;
          if(j > i) v = -1e9f;
        }
        p[nt][r] = __expf(v);
      }
    }

    __syncthreads();
    uint16_t* psw = ks + wave * 1024;
#pragma unroll
    for(int nt = 0; nt < 4; ++nt)
#pragma unroll
      for(int r = 0; r < 4; ++r){
        int rp2 = qd * 4 + r;
        int col = nt * 16 + ml;
        int c = (col >> 3) ^ (rp2 & 7);
        psw[rp2 * 64 + c * 8 + (col & 7)] = f2bf(p[nt][r]);
      }
#pragma unroll
    for(int kk2 = 0; kk2 < 2; ++kk2){
      int cp = (kk2 * 4 + qd) ^ (ml & 7);
      bf16x8 pa = load_frag(psw + ml * 64 + cp * 8);
#pragma unroll
      for(int dt = 0; dt < 13; ++dt){
        int row = dt * 16 + ml;
        int cv = (kk2 * 4 + qd) ^ (row & 7);
        bf16x8 vb = load_frag(vs + row * 64 + cv * 8);
        o[dt] = MFMA16x16(pa, vb, o[dt]);
      }
    }
  }

  const int hh = bh & 15, b = bh >> 4;
#pragma unroll
  for(int r = 0; r < 4; ++r){
    int i = qt * 64 + wave * 16 + qd * 4 + r;
    float inv = 1.0f / o[12][r];
    size_t obase = ((size_t)b * 2048 + i) * 3072 + hh * 192;
#pragma unroll
    for(int dt = 0; dt < 12; ++dt)
      attn_out[obase + dt * 16 + ml] = f2bf(o[dt][r] * inv);
  }
}

// ---------------- 5) out-proj GEMM: m97-style LDS-tiled, split-K=2 ----------
__global__ __launch_bounds__(256) void k_gemm_o_tile(const uint16_t* __restrict__ a,
                                                     const uint16_t* __restrict__ wt,
                                                     float* __restrict__ part){
  __shared__ __align__(16) uint16_t as[128 * 64];
  __shared__ __align__(16) uint16_t bs[128 * 64];
  const int wave = threadIdx.x >> 6, lane = threadIdx.x & 63;
  const int ml = lane & 15, qd = lane >> 4;
  const int m0 = blockIdx.y * 128, n0 = blockIdx.x * 128;
  const int kz = blockIdx.z;
  const int mo = (wave >> 1) * 64, no = (wave & 1) * 64;

  const int lrow = lane >> 3;
  const int gch  = (lane & 7) ^ (lrow & 7);
  const uint16_t* abase = a  + (size_t)(m0 + lrow) * 3072 + kz * 1536 + gch * 8;
  const uint16_t* bbase = wt + (size_t)(n0 + lrow) * 3072 + kz * 1536 + gch * 8;

  f32x4 acc[4][4];
#pragma unroll
  for(int mt = 0; mt < 4; ++mt)
#pragma unroll
    for(int nt = 0; nt < 4; ++nt) acc[mt][nt] = fzero();

  for(int kt = 0; kt < 24; ++kt){
    __syncthreads();
#pragma unroll
    for(int it = 0; it < 4; ++it){
      int seg = it * 4 + wave;
      gl2lds16(abase + (size_t)seg * 24576 + kt * 64, as + seg * 512);
      gl2lds16(bbase + (size_t)seg * 24576 + kt * 64, bs + seg * 512);
    }
    __syncthreads();
#pragma unroll
    for(int ks2 = 0; ks2 < 2; ++ks2){
      bf16x8 af[4], bfr[4];
#pragma unroll
      for(int mt = 0; mt < 4; ++mt){
        int row = mo + mt * 16 + ml;
        af[mt] = load_frag(as + row * 64 + (((ks2 * 4 + qd) ^ (row & 7)) * 8));
      }
#pragma unroll
      for(int nt = 0; nt < 4; ++nt){
        int row = no + nt * 16 + ml;
        bfr[nt] = load_frag(bs + row * 64 + (((ks2 * 4 + qd) ^ (row & 7)) * 8));
      }
#pragma unroll
      for(int mt = 0; mt < 4; ++mt)
#pragma unroll
        for(int nt = 0; nt < 4; ++nt)
          acc[mt][nt] = MFMA16x16(af[mt], bfr[nt], acc[mt][nt]);
    }
  }

  float* dst = part + (size_t)kz * 4096 * 1024;
#pragma unroll
  for(int mt = 0; mt < 4; ++mt)
#pragma unroll
    for(int nt = 0; nt < 4; ++nt)
#pragma unroll
      for(int r = 0; r < 4; ++r){
        int row = m0 + mo + mt * 16 + qd * 4 + r;
        int col = n0 + no + nt * 16 + ml;
        dst[(size_t)row * 1024 + col] = acc[mt][nt][r];
      }
}

// out = part0 + part1 (float4)
__global__ __launch_bounds__(256) void k_addout(const float* __restrict__ part,
                                                float* __restrict__ out){
  int i = blockIdx.x * 256 + threadIdx.x;
  const float4* p0 = (const float4*)part;
  const float4* p1 = p0 + (size_t)1048576;
  float4 a = p0[i], b = p1[i];
  float4 c; c.x = a.x + b.x; c.y = a.y + b.y; c.z = a.z + b.z; c.w = a.w + b.w;
  ((float4*)out)[i] = c;
}

// ---------------- launch ----------------

extern "C" void kernel_launch(void* const* d_in, const int* in_sizes, int n_in,
                              void* d_out, int out_size, void* d_ws, size_t ws_size,
                              hipStream_t stream) {
  (void)in_sizes; (void)n_in; (void)out_size; (void)ws_size;
  const float* x      = (const float*)d_in[0];
  const float* w_down = (const float*)d_in[2];
  const float* rms_w  = (const float*)d_in[3];
  const float* w_up   = (const float*)d_in[4];
  const float* w_o    = (const float*)d_in[5];
  float* out = (float*)d_out;

  char* ws = (char*)d_ws;
  uint16_t* h_bf   = (uint16_t*)(ws);                     // 1,572,864 B
  uint16_t* w_up_t = (uint16_t*)(ws + 1572864);           // 3,538,944 B
  uint16_t* w_o_t  = (uint16_t*)(ws + 5111808);           // 6,291,456 B
  uint16_t* w_dn_t = (uint16_t*)(ws + 11403264);          //   393,216 B
  uint16_t* q_tb   = (uint16_t*)(ws + 11796480);          // 25,165,824 B
  uint16_t* k_tb   = (uint16_t*)(ws + 36962304);          // 25,165,824 B
  uint16_t* v_tb   = (uint16_t*)(ws + 62128128);          // 25,165,824 B
  uint16_t* attnO  = (uint16_t*)(ws + 87293952);          // 25,165,824 B
  float*    part   = (float*)(ws + 11796480);             // alias q_tb/k_tb (dead after attn)

  k_transpose_cvt<<<dim3(288, 6), 256, 0, stream>>>(w_up, w_up_t, 192, 9216);
  k_transpose_cvt<<<dim3(32, 96), 256, 0, stream>>>(w_o,  w_o_t,  3072, 1024);
  k_transpose_cvt<<<dim3(6, 32),  256, 0, stream>>>(w_down, w_dn_t, 1024, 192);
  k_down_mfma<<<128, 256, 0, stream>>>(x, w_dn_t, rms_w, h_bf);
  k_gemm_up<<<dim3(18, 128), 256, 0, stream>>>(h_bf, w_up_t, q_tb, k_tb, v_tb);
  k_attn<<<1024, 256, 0, stream>>>(q_tb, k_tb, v_tb, attnO);
  k_gemm_o_tile<<<dim3(8, 32, 2), 256, 0, stream>>>(attnO, w_o_t, part);
  k_addout<<<4096, 256, 0, stream>>>(part, out);
}